// Round 6
// baseline (1272.131 us; speedup 1.0000x reference)
//
#include <hip/hip_runtime.h>
#include <math.h>

// CBTree contraction, B=4, L=9, d=256.
// g-combine before GEMM (linearity):
//   gL[p]=sum_b lc[b]*h[4p+b], gR[p]=sum_b rc[b]*h[4p+b]
//   h_new[p] = tanh([gL|gR] @ [Wl|Wr].T + vec[p])  (M=n_par, K=512, N=256)
//
// Round 6: round-5's hipLaunchCooperativeKernel never executed under the
// harness (d_out untouched -> absmax 1.0). Same single-kernel structure, but
// with a MANUAL persistent-kernel grid barrier:
//   grid=512, launch_bounds(256,2), LDS 30.7KB -> 2 blocks/CU capacity = 512
//   -> all blocks co-resident -> spin barrier is deadlock-free.
// Dedicated counter per phase (zeroed by a tiny init kernel each call; ws is
// re-poisoned 0xAA before every timed launch). Precision: bf16 hi/lo split
// (3 MFMAs per product), fp32 intermediates everywhere (ws is ~350MB).

typedef __bf16 bf16x8 __attribute__((ext_vector_type(8)));
typedef float f32x4 __attribute__((ext_vector_type(4)));

#define NWG 512u

__device__ __forceinline__ float fast_tanh(float x) {
    float ax = fabsf(x);
    float t = __builtin_amdgcn_exp2f(ax * -2.885390082f);  // 2*log2(e)
    float r = (1.0f - t) * __builtin_amdgcn_rcpf(1.0f + t);
    return copysignf(r, x);
}

__device__ __forceinline__ void split_bf16(float x, __bf16& hi, __bf16& lo) {
    hi = (__bf16)x;
    lo = (__bf16)(x - (float)hi);
}

// Grid barrier: one dedicated counter per use. All NWG blocks must arrive.
__device__ __forceinline__ void gbar(unsigned* ctr, int tid) {
    __syncthreads();          // block's stores issued & vmcnt drained
    __threadfence();          // device-scope release
    if (tid == 0) {
        atomicAdd(ctr, 1u);
        while (atomicAdd(ctr, 0u) < NWG) __builtin_amdgcn_s_sleep(16);
    }
    __syncthreads();
    __threadfence();          // device-scope acquire
}

__global__ void cbt_init(unsigned* ctrs) {
    if (threadIdx.x < 16) ctrs[threadIdx.x] = 0u;
}

// ---------------------------------------------------------------------------
// Block-GEMM level: tile BM x 128, wave-tile (BM/2) x 64, K-step 32 (16 T).
// A staged in LDS as hi/lo bf16 planes; B from pre-swizzled Wfh/Wfl
// (register double-buffered). 3-term split MFMA.
// ---------------------------------------------------------------------------
template <int BM>
__device__ void level_block(
    const float* __restrict__ h, const __bf16* __restrict__ Wfh,
    const __bf16* __restrict__ Wfl, const float* __restrict__ vec,
    float* __restrict__ out, int M, int wg, int tid, __bf16* Alds)
{
    const int nblocks = (M / BM) * 2;
    if (wg >= nblocks) return;

    constexpr int MI = BM / 32;
    constexpr int SE = (BM == 64) ? 8 : 4;
    constexpr int PL = BM * 40;           // LDS plane stride (elems)

    const int lane = tid & 63;
    const int w = tid >> 6;
    const int wr = w >> 1, wc = w & 1;
    const int mBase = (wg >> 1) * BM;
    const int nOff = (wg & 1) * 128;

    f32x4 acc[MI][4] = {};

    const int sm  = (BM == 64) ? (tid >> 2) : (tid >> 3);
    const int skq = (BM == 64) ? ((tid & 3) * 8) : ((tid & 7) * 4);
    const float* hb = h + (size_t)(mBase + sm) * 1024;

    float rr0[SE], rr1[SE], rr2[SE];
    float c0, c2;
    auto load_h = [&](int k0) {
        const bool isL = (k0 < 256);
        c0 = isL ? 1.0f : (1.0f / 3.0f);
        c2 = isL ? (1.0f / 3.0f) : 1.0f;
        const float* base = hb + (isL ? 0 : 256) + (k0 & 255) + skq;
#pragma unroll
        for (int v = 0; v < SE / 4; ++v) {
            const float4 a = *reinterpret_cast<const float4*>(base + v * 4);
            const float4 b = *reinterpret_cast<const float4*>(base + 256 + v * 4);
            const float4 c = *reinterpret_cast<const float4*>(base + 512 + v * 4);
            rr0[v*4+0] = a.x; rr0[v*4+1] = a.y; rr0[v*4+2] = a.z; rr0[v*4+3] = a.w;
            rr1[v*4+0] = b.x; rr1[v*4+1] = b.y; rr1[v*4+2] = b.z; rr1[v*4+3] = b.w;
            rr2[v*4+0] = c.x; rr2[v*4+1] = c.y; rr2[v*4+2] = c.z; rr2[v*4+3] = c.w;
        }
    };

    auto store_A = [&]() {
        constexpr float CM = 2.0f / 3.0f;
#pragma unroll
        for (int j = 0; j < SE; ++j) {
            const float g = c0 * rr0[j] + CM * rr1[j] + c2 * rr2[j];
            __bf16 hi, lo;
            split_bf16(g, hi, lo);
            Alds[sm * 40 + skq + j] = hi;
            Alds[PL + sm * 40 + skq + j] = lo;
        }
    };

    bf16x8 bh[2][4], bl[2][4];
    const size_t J0 = (size_t)(nOff >> 4) + wc * 4;
    auto load_B = [&](int T, int buf) {
        const size_t off = ((J0 * 16 + T) * 64 + lane) * 8;
#pragma unroll
        for (int j = 0; j < 4; ++j) {
            bh[buf][j] = *reinterpret_cast<const bf16x8*>(Wfh + off + (size_t)j * 8192);
            bl[buf][j] = *reinterpret_cast<const bf16x8*>(Wfl + off + (size_t)j * 8192);
        }
    };

    load_h(0);
    load_B(0, 0);

    for (int T = 0; T < 16; ++T) {
        __syncthreads();
        store_A();
        __syncthreads();

        if (T < 15) {
            load_B(T + 1, (T + 1) & 1);
            load_h((T + 1) * 32);
        }

        bf16x8 afh[MI], afl[MI];
#pragma unroll
        for (int i = 0; i < MI; ++i) {
            const int base = ((wr * MI + i) * 16 + (lane & 15)) * 40 + (lane >> 4) * 8;
            afh[i] = *reinterpret_cast<const bf16x8*>(&Alds[base]);
            afl[i] = *reinterpret_cast<const bf16x8*>(&Alds[PL + base]);
        }

        const int b = T & 1;
#pragma unroll
        for (int i = 0; i < MI; ++i)
#pragma unroll
            for (int j = 0; j < 4; ++j) {
                acc[i][j] = __builtin_amdgcn_mfma_f32_16x16x32_bf16(
                    afh[i], bl[b][j], acc[i][j], 0, 0, 0);
                acc[i][j] = __builtin_amdgcn_mfma_f32_16x16x32_bf16(
                    afl[i], bh[b][j], acc[i][j], 0, 0, 0);
                acc[i][j] = __builtin_amdgcn_mfma_f32_16x16x32_bf16(
                    afh[i], bh[b][j], acc[i][j], 0, 0, 0);
            }
    }

    // epilogue: C/D layout col=lane&15, row=(lane>>4)*4+reg
    const int q = lane >> 4, n16 = lane & 15;
#pragma unroll
    for (int i = 0; i < MI; ++i) {
        const int mrow = mBase + (wr * MI + i) * 16 + q * 4;
#pragma unroll
        for (int j = 0; j < 4; ++j) {
            const int n = nOff + wc * 64 + j * 16 + n16;
#pragma unroll
            for (int r = 0; r < 4; ++r) {
                const size_t idx = (size_t)(mrow + r) * 256 + n;
                out[idx] = fast_tanh(acc[i][j][r] + vec[idx]);
            }
        }
    }
}

// ---------------------------------------------------------------------------
// Unit path: one wave computes a 16m x 64n tile, K=512 (16 T), no LDS/barriers.
// ---------------------------------------------------------------------------
__device__ void level_units(
    const float* __restrict__ h, const __bf16* __restrict__ Wfh,
    const __bf16* __restrict__ Wfl, const float* __restrict__ vec,
    float* __restrict__ out, int M, int gwave, int lane, bool guard)
{
    const int U = ((M + 15) / 16) * 4;
    if (gwave >= U) return;

    const int mtile = gwave >> 2;
    const int nOff = (gwave & 3) * 64;
    const size_t J0 = (size_t)(nOff >> 4);

    const int mloc = lane & 15, q = lane >> 4;
    const int m = mtile * 16 + mloc;
    const bool valid = (m < M);
    const int mc = valid ? m : (M - 1);
    const float* hb = h + (size_t)mc * 1024 + q * 8;

    f32x4 acc[4] = {};

    float4 A0[2], A1[2], B0[2], B1[2], C0[2], C1[2];
    float cc0[2], cc2[2];
    bf16x8 ubh[2][4], ubl[2][4];

    auto load_h = [&](int T, int buf) {
        const int k0 = T * 32;
        const bool isL = (k0 < 256);
        cc0[buf] = isL ? 1.0f : (1.0f / 3.0f);
        cc2[buf] = isL ? (1.0f / 3.0f) : 1.0f;
        const float* base = hb + (isL ? 0 : 256) + (k0 & 255);
        A0[buf] = *reinterpret_cast<const float4*>(base);
        A1[buf] = *reinterpret_cast<const float4*>(base + 4);
        B0[buf] = *reinterpret_cast<const float4*>(base + 256);
        B1[buf] = *reinterpret_cast<const float4*>(base + 260);
        C0[buf] = *reinterpret_cast<const float4*>(base + 512);
        C1[buf] = *reinterpret_cast<const float4*>(base + 516);
    };
    auto load_B = [&](int T, int buf) {
        const size_t off = ((J0 * 16 + T) * 64 + lane) * 8;
#pragma unroll
        for (int j = 0; j < 4; ++j) {
            ubh[buf][j] = *reinterpret_cast<const bf16x8*>(Wfh + off + (size_t)j * 8192);
            ubl[buf][j] = *reinterpret_cast<const bf16x8*>(Wfl + off + (size_t)j * 8192);
        }
    };

    load_h(0, 0);
    load_B(0, 0);

    for (int T = 0; T < 16; ++T) {
        const int b = T & 1;
        if (T < 15) { load_h(T + 1, b ^ 1); load_B(T + 1, b ^ 1); }

        constexpr float CM = 2.0f / 3.0f;
        float g[8];
        g[0] = cc0[b] * A0[b].x + CM * B0[b].x + cc2[b] * C0[b].x;
        g[1] = cc0[b] * A0[b].y + CM * B0[b].y + cc2[b] * C0[b].y;
        g[2] = cc0[b] * A0[b].z + CM * B0[b].z + cc2[b] * C0[b].z;
        g[3] = cc0[b] * A0[b].w + CM * B0[b].w + cc2[b] * C0[b].w;
        g[4] = cc0[b] * A1[b].x + CM * B1[b].x + cc2[b] * C1[b].x;
        g[5] = cc0[b] * A1[b].y + CM * B1[b].y + cc2[b] * C1[b].y;
        g[6] = cc0[b] * A1[b].z + CM * B1[b].z + cc2[b] * C1[b].z;
        g[7] = cc0[b] * A1[b].w + CM * B1[b].w + cc2[b] * C1[b].w;

        bf16x8 ah, al;
#pragma unroll
        for (int j = 0; j < 8; ++j) {
            const float gv = valid ? g[j] : 0.0f;
            __bf16 hi, lo;
            split_bf16(gv, hi, lo);
            ah[j] = hi; al[j] = lo;
        }

#pragma unroll
        for (int j = 0; j < 4; ++j) {
            acc[j] = __builtin_amdgcn_mfma_f32_16x16x32_bf16(ah, ubl[b][j], acc[j], 0, 0, 0);
            acc[j] = __builtin_amdgcn_mfma_f32_16x16x32_bf16(al, ubh[b][j], acc[j], 0, 0, 0);
            acc[j] = __builtin_amdgcn_mfma_f32_16x16x32_bf16(ah, ubh[b][j], acc[j], 0, 0, 0);
        }
    }

    const int n16 = lane & 15;
#pragma unroll
    for (int j = 0; j < 4; ++j) {
        const int n = nOff + j * 16 + n16;
#pragma unroll
        for (int r = 0; r < 4; ++r) {
            const int mr = mtile * 16 + q * 4 + r;
            if (!guard || mr < M) {
                const size_t idx = (size_t)mr * 256 + n;
                out[idx] = fast_tanh(acc[j][r] + vec[idx]);
            }
        }
    }
}

// ---------------------------------------------------------------------------
// Whole tree, one persistent kernel. grid = 512 x 256 (2 blocks/CU resident).
// ---------------------------------------------------------------------------
__global__ __launch_bounds__(256, 2) void cbt_persist(
    const float* __restrict__ vectors, const float* __restrict__ Wl,
    const float* __restrict__ Wr, float* __restrict__ d_out,
    float* __restrict__ ws, unsigned* __restrict__ ctrs)
{
    // ws layout (fp32, distinct regions; ws is ~350MB)
    float* h7 = ws;                                  // 16384 x 256
    float* h6 = h7 + (size_t)16384 * 256;            //  4096 x 256
    float* h5 = h6 + (size_t)4096 * 256;             //  1024 x 256
    float* h4 = h5 + (size_t)1024 * 256;             //   256 x 256
    float* h3 = h4 + (size_t)256 * 256;              //    64 x 256
    __bf16* Wfh = (__bf16*)(h3 + (size_t)64 * 256);  // 131072 bf16
    __bf16* Wfl = Wfh + 131072;

    const float* vec7 = vectors + (size_t)5461 * 256;
    const float* vec6 = vectors + (size_t)1365 * 256;
    const float* vec5 = vectors + (size_t)341 * 256;
    const float* vec4 = vectors + (size_t)85 * 256;
    const float* vec3 = vectors + (size_t)21 * 256;
    const float* vec2 = vectors + (size_t)5 * 256;
    const float* vec1 = vectors + (size_t)1 * 256;
    const float* vec0 = vectors;
    const float* leaf = vectors + (size_t)21845 * 256;

    __shared__ __align__(16) __bf16 Alds[2 * 64 * 40];
    __shared__ __align__(16) float l2out[16 * 256];
    __shared__ __align__(16) float l1out[4 * 256];

    const int wg = blockIdx.x;
    const int tid = threadIdx.x;
    const int lane = tid & 63;
    const int gwave = wg * 4 + (tid >> 6);

    // ---- Phase W: swizzle [Wl|Wr] -> MFMA B-fragment order, hi/lo bf16 ----
    {
        const int t = wg * 256 + tid;
        if (t < 16384) {
            const int L = t & 63;
            const int TJ = t >> 6;
            const int T = TJ & 15;
            const int J = TJ >> 4;
            const int n = J * 16 + (L & 15);
            const int k = T * 32 + (L >> 4) * 8;
            const float* src = (k < 256) ? (Wl + (size_t)n * 256 + k)
                                         : (Wr + (size_t)n * 256 + (k - 256));
            const float4 f0 = *reinterpret_cast<const float4*>(src);
            const float4 f1 = *reinterpret_cast<const float4*>(src + 4);
            const float v[8] = {f0.x, f0.y, f0.z, f0.w, f1.x, f1.y, f1.z, f1.w};
            bf16x8 oh, ol;
#pragma unroll
            for (int j = 0; j < 8; ++j) {
                __bf16 hi, lo;
                split_bf16(v[j], hi, lo);
                oh[j] = hi; ol[j] = lo;
            }
            *reinterpret_cast<bf16x8*>(Wfh + (size_t)t * 8) = oh;
            *reinterpret_cast<bf16x8*>(Wfl + (size_t)t * 8) = ol;
        }
    }
    gbar(&ctrs[0], tid);

    level_block<64>(leaf, Wfh, Wfl, vec7, h7, 16384, wg, tid, Alds);
    gbar(&ctrs[1], tid);

    level_block<32>(h7, Wfh, Wfl, vec6, h6, 4096, wg, tid, Alds);
    gbar(&ctrs[2], tid);

    level_units(h6, Wfh, Wfl, vec5, h5, 1024, gwave, lane, false);
    gbar(&ctrs[3], tid);

    level_units(h5, Wfh, Wfl, vec4, h4, 256, gwave, lane, false);
    gbar(&ctrs[4], tid);

    level_units(h4, Wfh, Wfl, vec3, h3, 64, gwave, lane, false);
    gbar(&ctrs[5], tid);

    // ---- Finale: L2, L1, L0 in workgroup 0 (LDS ping-pong) ----
    if (wg == 0) {
        const int lw = tid >> 6;
        level_units(h3, Wfh, Wfl, vec2, l2out, 16, lw, lane, false);
        __syncthreads();
        level_units(l2out, Wfh, Wfl, vec1, l1out, 4, lw, lane, true);
        __syncthreads();
        level_units(l1out, Wfh, Wfl, vec0, d_out, 1, lw, lane, true);
    }
}

// ---------------------------------------------------------------------------
extern "C" void kernel_launch(void* const* d_in, const int* in_sizes, int n_in,
                              void* d_out, int out_size, void* d_ws, size_t ws_size,
                              hipStream_t stream) {
    const float* vectors = (const float*)d_in[0];
    const float* Wl = (const float*)d_in[1];
    const float* Wr = (const float*)d_in[2];
    float* out = (float*)d_out;
    float* ws = (float*)d_ws;
    // barrier counters far past the ~22MB of live buffers (ws ~350MB)
    unsigned* ctrs = (unsigned*)((char*)d_ws + ((size_t)64 << 20));

    hipLaunchKernelGGL(cbt_init, dim3(1), dim3(64), 0, stream, ctrs);
    hipLaunchKernelGGL(cbt_persist, dim3(512), dim3(256), 0, stream,
                       vectors, Wl, Wr, out, ws, ctrs);
}

// Round 7
// 1183.651 us; speedup vs baseline: 1.0748x; 1.0748x over previous
//
#include <hip/hip_runtime.h>
#include <math.h>

// CBTree contraction, B=4, L=9, d=256.
// g-combine before GEMM (linearity):
//   gL[p]=sum_b lc[b]*h[4p+b], gR[p]=sum_b rc[b]*h[4p+b]
//   h_new[p] = tanh([gL|gR] @ [Wl|Wr].T + vec[p])  (M=n_par, K=512, N=256)
//
// Round 7: multi-launch again (round-6 persistent-kernel grid barriers cost
// ~170us each: device fences flush non-coherent per-XCD L2s -> 142MB refetch,
// RMW-spin serializes one line). 6 launches instead of round-4's 9:
//   Wswz | L7 block-GEMM | L6 block-GEMM | L5 units | L4 units | fused tail
// Tail = L3->L2->L1->L0 in ONE 1024-thread block, intermediates in LDS (84KB),
// __syncthreads between levels. Precision: round-6-validated bf16 hi/lo split
// (3 MFMAs/product) + fp32 intermediates -> absmax ~2.4e-4.

typedef __bf16 bf16x8 __attribute__((ext_vector_type(8)));
typedef float f32x4 __attribute__((ext_vector_type(4)));

__device__ __forceinline__ float fast_tanh(float x) {
    float ax = fabsf(x);
    float t = __builtin_amdgcn_exp2f(ax * -2.885390082f);  // 2*log2(e)
    float r = (1.0f - t) * __builtin_amdgcn_rcpf(1.0f + t);
    return copysignf(r, x);
}

__device__ __forceinline__ void split_bf16(float x, __bf16& hi, __bf16& lo) {
    hi = (__bf16)x;
    lo = (__bf16)(x - (float)hi);
}

// ---------------------------------------------------------------------------
// W swizzle: [Wl|Wr] (N=256 x K=512) -> MFMA B-fragment order, hi/lo planes.
// Fragment (J,T), lane L, elem j: B[k=T*32+(L>>4)*8+j][n=J*16+(L&15)] = Wcat[n][k]
// ---------------------------------------------------------------------------
__global__ __launch_bounds__(256) void cbt_wconv(
    const float* __restrict__ Wl, const float* __restrict__ Wr,
    __bf16* __restrict__ Wfh, __bf16* __restrict__ Wfl)
{
    const int t = blockIdx.x * 256 + threadIdx.x;   // 0..16383
    const int L = t & 63;
    const int TJ = t >> 6;
    const int T = TJ & 15;
    const int J = TJ >> 4;
    const int n = J * 16 + (L & 15);
    const int k = T * 32 + (L >> 4) * 8;
    const float* src = (k < 256) ? (Wl + (size_t)n * 256 + k)
                                 : (Wr + (size_t)n * 256 + (k - 256));
    const float4 f0 = *reinterpret_cast<const float4*>(src);
    const float4 f1 = *reinterpret_cast<const float4*>(src + 4);
    const float v[8] = {f0.x, f0.y, f0.z, f0.w, f1.x, f1.y, f1.z, f1.w};
    bf16x8 oh, ol;
#pragma unroll
    for (int j = 0; j < 8; ++j) {
        __bf16 hi, lo;
        split_bf16(v[j], hi, lo);
        oh[j] = hi; ol[j] = lo;
    }
    *reinterpret_cast<bf16x8*>(Wfh + (size_t)t * 8) = oh;
    *reinterpret_cast<bf16x8*>(Wfl + (size_t)t * 8) = ol;
}

// ---------------------------------------------------------------------------
// Block-GEMM level: tile BM x 128, wave-tile (BM/2) x 64, K-step 32 (16 T).
// A staged in LDS hi/lo bf16 planes; B register-double-buffered from Wfh/Wfl.
// 3-term split MFMA. grid = (M/BM)*2 blocks of 256. [R6-validated]
// ---------------------------------------------------------------------------
template <int BM>
__global__ __launch_bounds__(256, 2) void cbt_block(
    const float* __restrict__ h, const __bf16* __restrict__ Wfh,
    const __bf16* __restrict__ Wfl, const float* __restrict__ vec,
    float* __restrict__ out, int M)
{
    constexpr int MI = BM / 32;
    constexpr int SE = (BM == 64) ? 8 : 4;
    constexpr int PL = BM * 40;           // LDS plane stride (elems)
    __shared__ __align__(16) __bf16 Alds[2 * BM * 40];

    const int tid = threadIdx.x;
    const int wg = blockIdx.x;
    const int lane = tid & 63;
    const int w = tid >> 6;
    const int wr = w >> 1, wc = w & 1;
    const int mBase = (wg >> 1) * BM;
    const int nOff = (wg & 1) * 128;

    f32x4 acc[MI][4] = {};

    const int sm  = (BM == 64) ? (tid >> 2) : (tid >> 3);
    const int skq = (BM == 64) ? ((tid & 3) * 8) : ((tid & 7) * 4);
    const float* hb = h + (size_t)(mBase + sm) * 1024;

    float rr0[SE], rr1[SE], rr2[SE];
    float c0, c2;
    auto load_h = [&](int k0) {
        const bool isL = (k0 < 256);
        c0 = isL ? 1.0f : (1.0f / 3.0f);
        c2 = isL ? (1.0f / 3.0f) : 1.0f;
        const float* base = hb + (isL ? 0 : 256) + (k0 & 255) + skq;
#pragma unroll
        for (int v = 0; v < SE / 4; ++v) {
            const float4 a = *reinterpret_cast<const float4*>(base + v * 4);
            const float4 b = *reinterpret_cast<const float4*>(base + 256 + v * 4);
            const float4 c = *reinterpret_cast<const float4*>(base + 512 + v * 4);
            rr0[v*4+0] = a.x; rr0[v*4+1] = a.y; rr0[v*4+2] = a.z; rr0[v*4+3] = a.w;
            rr1[v*4+0] = b.x; rr1[v*4+1] = b.y; rr1[v*4+2] = b.z; rr1[v*4+3] = b.w;
            rr2[v*4+0] = c.x; rr2[v*4+1] = c.y; rr2[v*4+2] = c.z; rr2[v*4+3] = c.w;
        }
    };

    auto store_A = [&]() {
        constexpr float CM = 2.0f / 3.0f;
#pragma unroll
        for (int j = 0; j < SE; ++j) {
            const float g = c0 * rr0[j] + CM * rr1[j] + c2 * rr2[j];
            __bf16 hi, lo;
            split_bf16(g, hi, lo);
            Alds[sm * 40 + skq + j] = hi;
            Alds[PL + sm * 40 + skq + j] = lo;
        }
    };

    bf16x8 bh[2][4], bl[2][4];
    const size_t J0 = (size_t)(nOff >> 4) + wc * 4;
    auto load_B = [&](int T, int buf) {
        const size_t off = ((J0 * 16 + T) * 64 + lane) * 8;
#pragma unroll
        for (int j = 0; j < 4; ++j) {
            bh[buf][j] = *reinterpret_cast<const bf16x8*>(Wfh + off + (size_t)j * 8192);
            bl[buf][j] = *reinterpret_cast<const bf16x8*>(Wfl + off + (size_t)j * 8192);
        }
    };

    load_h(0);
    load_B(0, 0);

    for (int T = 0; T < 16; ++T) {
        __syncthreads();
        store_A();
        __syncthreads();

        if (T < 15) {
            load_B(T + 1, (T + 1) & 1);
            load_h((T + 1) * 32);
        }

        bf16x8 afh[MI], afl[MI];
#pragma unroll
        for (int i = 0; i < MI; ++i) {
            const int base = ((wr * MI + i) * 16 + (lane & 15)) * 40 + (lane >> 4) * 8;
            afh[i] = *reinterpret_cast<const bf16x8*>(&Alds[base]);
            afl[i] = *reinterpret_cast<const bf16x8*>(&Alds[PL + base]);
        }

        const int b = T & 1;
#pragma unroll
        for (int i = 0; i < MI; ++i)
#pragma unroll
            for (int j = 0; j < 4; ++j) {
                acc[i][j] = __builtin_amdgcn_mfma_f32_16x16x32_bf16(
                    afh[i], bl[b][j], acc[i][j], 0, 0, 0);
                acc[i][j] = __builtin_amdgcn_mfma_f32_16x16x32_bf16(
                    afl[i], bh[b][j], acc[i][j], 0, 0, 0);
                acc[i][j] = __builtin_amdgcn_mfma_f32_16x16x32_bf16(
                    afh[i], bh[b][j], acc[i][j], 0, 0, 0);
            }
    }

    // epilogue: C/D layout col=lane&15, row=(lane>>4)*4+reg
    const int q = lane >> 4, n16 = lane & 15;
#pragma unroll
    for (int i = 0; i < MI; ++i) {
        const int mrow = mBase + (wr * MI + i) * 16 + q * 4;
#pragma unroll
        for (int j = 0; j < 4; ++j) {
            const int n = nOff + wc * 64 + j * 16 + n16;
#pragma unroll
            for (int r = 0; r < 4; ++r) {
                const size_t idx = (size_t)(mrow + r) * 256 + n;
                out[idx] = fast_tanh(acc[i][j][r] + vec[idx]);
            }
        }
    }
}

// ---------------------------------------------------------------------------
// Unit: one wave computes a 16m x 64n tile, K=512 (16 T), no LDS/barriers.
// Returns normally for gwave >= U (caller may __syncthreads after).
// [R6-validated]
// ---------------------------------------------------------------------------
__device__ void level_units(
    const float* __restrict__ h, const __bf16* __restrict__ Wfh,
    const __bf16* __restrict__ Wfl, const float* __restrict__ vec,
    float* __restrict__ out, int M, int gwave, int lane, bool guard)
{
    const int U = ((M + 15) / 16) * 4;
    if (gwave >= U) return;

    const int mtile = gwave >> 2;
    const int nOff = (gwave & 3) * 64;
    const size_t J0 = (size_t)(nOff >> 4);

    const int mloc = lane & 15, q = lane >> 4;
    const int m = mtile * 16 + mloc;
    const bool valid = (m < M);
    const int mc = valid ? m : (M - 1);
    const float* hb = h + (size_t)mc * 1024 + q * 8;

    f32x4 acc[4] = {};

    float4 A0[2], A1[2], B0[2], B1[2], C0[2], C1[2];
    float cc0[2], cc2[2];
    bf16x8 ubh[2][4], ubl[2][4];

    auto load_h = [&](int T, int buf) {
        const int k0 = T * 32;
        const bool isL = (k0 < 256);
        cc0[buf] = isL ? 1.0f : (1.0f / 3.0f);
        cc2[buf] = isL ? (1.0f / 3.0f) : 1.0f;
        const float* base = hb + (isL ? 0 : 256) + (k0 & 255);
        A0[buf] = *reinterpret_cast<const float4*>(base);
        A1[buf] = *reinterpret_cast<const float4*>(base + 4);
        B0[buf] = *reinterpret_cast<const float4*>(base + 256);
        B1[buf] = *reinterpret_cast<const float4*>(base + 260);
        C0[buf] = *reinterpret_cast<const float4*>(base + 512);
        C1[buf] = *reinterpret_cast<const float4*>(base + 516);
    };
    auto load_B = [&](int T, int buf) {
        const size_t off = ((J0 * 16 + T) * 64 + lane) * 8;
#pragma unroll
        for (int j = 0; j < 4; ++j) {
            ubh[buf][j] = *reinterpret_cast<const bf16x8*>(Wfh + off + (size_t)j * 8192);
            ubl[buf][j] = *reinterpret_cast<const bf16x8*>(Wfl + off + (size_t)j * 8192);
        }
    };

    load_h(0, 0);
    load_B(0, 0);

    for (int T = 0; T < 16; ++T) {
        const int b = T & 1;
        if (T < 15) { load_h(T + 1, b ^ 1); load_B(T + 1, b ^ 1); }

        constexpr float CM = 2.0f / 3.0f;
        float g[8];
        g[0] = cc0[b] * A0[b].x + CM * B0[b].x + cc2[b] * C0[b].x;
        g[1] = cc0[b] * A0[b].y + CM * B0[b].y + cc2[b] * C0[b].y;
        g[2] = cc0[b] * A0[b].z + CM * B0[b].z + cc2[b] * C0[b].z;
        g[3] = cc0[b] * A0[b].w + CM * B0[b].w + cc2[b] * C0[b].w;
        g[4] = cc0[b] * A1[b].x + CM * B1[b].x + cc2[b] * C1[b].x;
        g[5] = cc0[b] * A1[b].y + CM * B1[b].y + cc2[b] * C1[b].y;
        g[6] = cc0[b] * A1[b].z + CM * B1[b].z + cc2[b] * C1[b].z;
        g[7] = cc0[b] * A1[b].w + CM * B1[b].w + cc2[b] * C1[b].w;

        bf16x8 ah, al;
#pragma unroll
        for (int j = 0; j < 8; ++j) {
            const float gv = valid ? g[j] : 0.0f;
            __bf16 hi, lo;
            split_bf16(gv, hi, lo);
            ah[j] = hi; al[j] = lo;
        }

#pragma unroll
        for (int j = 0; j < 4; ++j) {
            acc[j] = __builtin_amdgcn_mfma_f32_16x16x32_bf16(ah, ubl[b][j], acc[j], 0, 0, 0);
            acc[j] = __builtin_amdgcn_mfma_f32_16x16x32_bf16(al, ubh[b][j], acc[j], 0, 0, 0);
            acc[j] = __builtin_amdgcn_mfma_f32_16x16x32_bf16(ah, ubh[b][j], acc[j], 0, 0, 0);
        }
    }

    const int n16 = lane & 15;
#pragma unroll
    for (int j = 0; j < 4; ++j) {
        const int n = nOff + j * 16 + n16;
#pragma unroll
        for (int r = 0; r < 4; ++r) {
            const int mr = mtile * 16 + q * 4 + r;
            if (!guard || mr < M) {
                const size_t idx = (size_t)mr * 256 + n;
                out[idx] = fast_tanh(acc[j][r] + vec[idx]);
            }
        }
    }
}

// Standalone wave-unit level: grid = U/4 blocks of 256.
__global__ __launch_bounds__(256, 2) void cbt_units(
    const float* __restrict__ h, const __bf16* __restrict__ Wfh,
    const __bf16* __restrict__ Wfl, const float* __restrict__ vec,
    float* __restrict__ out, int M)
{
    const int gwave = blockIdx.x * 4 + (threadIdx.x >> 6);
    level_units(h, Wfh, Wfl, vec, out, M, gwave, threadIdx.x & 63, false);
}

// ---------------------------------------------------------------------------
// Fused tail: L3 -> L2 -> L1 -> L0 in ONE 1024-thread block (16 waves).
// Intermediates in LDS (64+16+4 KB). __syncthreads between levels — all
// threads reach it (inactive waves return from level_units first).
// ---------------------------------------------------------------------------
__global__ __launch_bounds__(1024) void cbt_tail(
    const float* __restrict__ h4, const __bf16* __restrict__ Wfh,
    const __bf16* __restrict__ Wfl, const float* __restrict__ vectors,
    float* __restrict__ d_out)
{
    __shared__ __align__(16) float h3s[64 * 256];
    __shared__ __align__(16) float h2s[16 * 256];
    __shared__ __align__(16) float h1s[4 * 256];

    const int tid = threadIdx.x;
    const int lane = tid & 63;
    const int lw = tid >> 6;   // 0..15

    const float* vec3 = vectors + (size_t)21 * 256;
    const float* vec2 = vectors + (size_t)5 * 256;
    const float* vec1 = vectors + (size_t)1 * 256;
    const float* vec0 = vectors;

    level_units(h4, Wfh, Wfl, vec3, h3s, 64, lw, lane, false);   // 16 units
    __syncthreads();
    level_units(h3s, Wfh, Wfl, vec2, h2s, 16, lw, lane, false);  // 4 units
    __syncthreads();
    level_units(h2s, Wfh, Wfl, vec1, h1s, 4, lw, lane, true);    // 4 units
    __syncthreads();
    level_units(h1s, Wfh, Wfl, vec0, d_out, 1, lw, lane, true);  // 4 units
}

// ---------------------------------------------------------------------------
extern "C" void kernel_launch(void* const* d_in, const int* in_sizes, int n_in,
                              void* d_out, int out_size, void* d_ws, size_t ws_size,
                              hipStream_t stream) {
    const float* vectors = (const float*)d_in[0];
    const float* Wl = (const float*)d_in[1];
    const float* Wr = (const float*)d_in[2];
    float* out = (float*)d_out;

    // ws layout (fp32 intermediates, distinct regions; ws ~350MB)
    float* h7 = (float*)d_ws;                        // 16384 x 256
    float* h6 = h7 + (size_t)16384 * 256;            //  4096 x 256
    float* h5 = h6 + (size_t)4096 * 256;             //  1024 x 256
    float* h4 = h5 + (size_t)1024 * 256;             //   256 x 256
    __bf16* Wfh = (__bf16*)(h4 + (size_t)256 * 256); // 131072 bf16
    __bf16* Wfl = Wfh + 131072;

    const float* vec7 = vectors + (size_t)5461 * 256;
    const float* vec6 = vectors + (size_t)1365 * 256;
    const float* vec5 = vectors + (size_t)341 * 256;
    const float* vec4 = vectors + (size_t)85 * 256;
    const float* leaf = vectors + (size_t)21845 * 256;

    hipLaunchKernelGGL(cbt_wconv, dim3(64), dim3(256), 0, stream, Wl, Wr, Wfh, Wfl);
    hipLaunchKernelGGL((cbt_block<64>), dim3(512), dim3(256), 0, stream,
                       leaf, Wfh, Wfl, vec7, h7, 16384);
    hipLaunchKernelGGL((cbt_block<32>), dim3(256), dim3(256), 0, stream,
                       h7, Wfh, Wfl, vec6, h6, 4096);
    hipLaunchKernelGGL(cbt_units, dim3(64), dim3(256), 0, stream,
                       h6, Wfh, Wfl, vec5, h5, 1024);
    hipLaunchKernelGGL(cbt_units, dim3(16), dim3(256), 0, stream,
                       h5, Wfh, Wfl, vec4, h4, 256);
    hipLaunchKernelGGL(cbt_tail, dim3(1), dim3(1024), 0, stream,
                       h4, Wfh, Wfl, vectors, out);
}

// Round 8
// 326.349 us; speedup vs baseline: 3.8981x; 3.6270x over previous
//
#include <hip/hip_runtime.h>
#include <math.h>

// CBTree contraction, B=4, L=9, d=256.
// g-combine before GEMM (linearity):
//   gL[p]=sum_b lc[b]*h[4p+b], gR[p]=sum_b rc[b]*h[4p+b]
//   h_new[p] = tanh([gL|gR] @ [Wl|Wr].T + vec[p])  (M=n_par, K=512, N=256)
//
// Round 8: the round-6/7 hi/lo-split block kernel was pathologically slow
// (796us for L7 vs <53us in round 4; 3x chained MFMAs + 64 VGPRs of hi/lo B
// double-buffer + 16 scalar b16 LDS stores). Revert to the round-4-proven
// single-MFMA structure, but in FP16 instead of BF16:
//   - all values here are O(1) (tanh-bounded h, |g|<=2, |W|~0.06): f16 range
//     is a non-issue, and f16 quant error (2^-11) is 8x finer than bf16.
//   - fp32 intermediates (removes R4's bf16-storage error).
// Predicted absmax ~2e-3 (R4 bf16 measured 0.0195; /8 mantissa + no storage).
// 6 launches: Wswz | L7 BM=64 | L6 BM=32 | L5 units | L4 units | fused tail.

typedef _Float16 f16x8 __attribute__((ext_vector_type(8)));
typedef _Float16 f16x4 __attribute__((ext_vector_type(4)));
typedef float f32x4 __attribute__((ext_vector_type(4)));

__device__ __forceinline__ float fast_tanh(float x) {
    float ax = fabsf(x);
    float t = __builtin_amdgcn_exp2f(ax * -2.885390082f);  // 2*log2(e)
    float r = (1.0f - t) * __builtin_amdgcn_rcpf(1.0f + t);
    return copysignf(r, x);
}

// ---------------------------------------------------------------------------
// W swizzle: [Wl|Wr] (N=256 x K=512) -> MFMA B-fragment order, f16.
// Fragment (J,T), lane L, elem j: B[k=T*32+(L>>4)*8+j][n=J*16+(L&15)] = Wcat[n][k]
// Flat: Wf[(((J*16)+T)*64 + L)*8 + j]
// ---------------------------------------------------------------------------
__global__ __launch_bounds__(256) void cbt_wconv(
    const float* __restrict__ Wl, const float* __restrict__ Wr,
    _Float16* __restrict__ Wf)
{
    const int t = blockIdx.x * 256 + threadIdx.x;   // 0..16383
    const int L = t & 63;
    const int TJ = t >> 6;
    const int T = TJ & 15;
    const int J = TJ >> 4;
    const int n = J * 16 + (L & 15);
    const int k = T * 32 + (L >> 4) * 8;
    const float* src = (k < 256) ? (Wl + (size_t)n * 256 + k)
                                 : (Wr + (size_t)n * 256 + (k - 256));
    const float4 f0 = *reinterpret_cast<const float4*>(src);
    const float4 f1 = *reinterpret_cast<const float4*>(src + 4);
    f16x8 o;
    o[0] = (_Float16)f0.x; o[1] = (_Float16)f0.y;
    o[2] = (_Float16)f0.z; o[3] = (_Float16)f0.w;
    o[4] = (_Float16)f1.x; o[5] = (_Float16)f1.y;
    o[6] = (_Float16)f1.z; o[7] = (_Float16)f1.w;
    *reinterpret_cast<f16x8*>(Wf + (size_t)t * 8) = o;
}

// ---------------------------------------------------------------------------
// Block-GEMM level (R4-fast structure, f16): tile BM x 128, grid(M/BM, 2),
// 256 threads (4 waves), wave-tile (BM/2) x 64, K-step 32 (16 T).
// A (combined g, f16) via LDS (vectorized stores); B register-double-buffered
// coalesced loads from Wf (L2-hot). Single MFMA per product.
// ---------------------------------------------------------------------------
template <int BM>
__global__ __launch_bounds__(256, 2) void cbt_block(
    const float* __restrict__ h,       // (4*M, 256) children, fp32
    const _Float16* __restrict__ Wf,   // swizzled weights
    const float* __restrict__ vec,     // (M, 256)
    float* __restrict__ out,           // (M, 256) fp32
    int M)
{
    constexpr int MI = BM / 32;              // m-tiles per wave
    constexpr int SE = (BM == 64) ? 8 : 4;   // A elems staged per thread
    __shared__ __align__(16) _Float16 Alds[BM * 40];  // rows of 32, stride 40

    const int tid = threadIdx.x;
    const int lane = tid & 63;
    const int w = tid >> 6;
    const int wr = w >> 1, wc = w & 1;
    const int mBase = blockIdx.x * BM;
    const int nOff = blockIdx.y * 128;

    f32x4 acc[MI][4] = {};

    // A staging geometry
    const int sm  = (BM == 64) ? (tid >> 2) : (tid >> 3);
    const int skq = (BM == 64) ? ((tid & 3) * 8) : ((tid & 7) * 4);
    const float* hb = h + (size_t)(mBase + sm) * 1024;

    float rr0[SE], rr1[SE], rr2[SE];
    float c0, c2;
    auto load_h = [&](int k0) {
        const bool isL = (k0 < 256);
        c0 = isL ? 1.0f : (1.0f / 3.0f);
        c2 = isL ? (1.0f / 3.0f) : 1.0f;
        const float* base = hb + (isL ? 0 : 256) + (k0 & 255) + skq;
#pragma unroll
        for (int v = 0; v < SE / 4; ++v) {
            const float4 a = *reinterpret_cast<const float4*>(base + v * 4);
            const float4 b = *reinterpret_cast<const float4*>(base + 256 + v * 4);
            const float4 c = *reinterpret_cast<const float4*>(base + 512 + v * 4);
            rr0[v*4+0] = a.x; rr0[v*4+1] = a.y; rr0[v*4+2] = a.z; rr0[v*4+3] = a.w;
            rr1[v*4+0] = b.x; rr1[v*4+1] = b.y; rr1[v*4+2] = b.z; rr1[v*4+3] = b.w;
            rr2[v*4+0] = c.x; rr2[v*4+1] = c.y; rr2[v*4+2] = c.z; rr2[v*4+3] = c.w;
        }
    };

    auto store_A = [&]() {
        constexpr float CM = 2.0f / 3.0f;
        if constexpr (SE == 8) {
            f16x8 g;
#pragma unroll
            for (int j = 0; j < 8; ++j)
                g[j] = (_Float16)(c0 * rr0[j] + CM * rr1[j] + c2 * rr2[j]);
            *reinterpret_cast<f16x8*>(&Alds[sm * 40 + skq]) = g;
        } else {
            f16x4 g;
#pragma unroll
            for (int j = 0; j < 4; ++j)
                g[j] = (_Float16)(c0 * rr0[j] + CM * rr1[j] + c2 * rr2[j]);
            *reinterpret_cast<f16x4*>(&Alds[sm * 40 + skq]) = g;
        }
    };

    // B fragments: double-buffered registers, coalesced loads (L2-hot)
    f16x8 bfr[2][4];
    const size_t J0 = (size_t)(nOff >> 4) + wc * 4;
    auto load_B = [&](int T, int buf) {
        const _Float16* p = Wf + ((J0 * 16 + T) * 64 + lane) * 8;
#pragma unroll
        for (int j = 0; j < 4; ++j)
            bfr[buf][j] = *reinterpret_cast<const f16x8*>(p + (size_t)j * 8192);
    };

    load_h(0);
    load_B(0, 0);

    for (int T = 0; T < 16; ++T) {
        __syncthreads();
        store_A();
        __syncthreads();

        if (T < 15) {                 // prefetch next tile into regs
            load_B(T + 1, (T + 1) & 1);
            load_h((T + 1) * 32);
        }

        f16x8 af[MI];
#pragma unroll
        for (int i = 0; i < MI; ++i)
            af[i] = *reinterpret_cast<const f16x8*>(
                &Alds[((wr * MI + i) * 16 + (lane & 15)) * 40 + (lane >> 4) * 8]);

#pragma unroll
        for (int i = 0; i < MI; ++i)
#pragma unroll
            for (int j = 0; j < 4; ++j)
                acc[i][j] = __builtin_amdgcn_mfma_f32_16x16x32_f16(
                    af[i], bfr[T & 1][j], acc[i][j], 0, 0, 0);
    }

    // epilogue: C/D layout col=lane&15, row=(lane>>4)*4+reg
    const int q = lane >> 4, n16 = lane & 15;
#pragma unroll
    for (int i = 0; i < MI; ++i) {
        const int mrow = mBase + (wr * MI + i) * 16 + q * 4;
#pragma unroll
        for (int j = 0; j < 4; ++j) {
            const int n = nOff + wc * 64 + j * 16 + n16;
#pragma unroll
            for (int r = 0; r < 4; ++r) {
                const size_t idx = (size_t)(mrow + r) * 256 + n;
                out[idx] = fast_tanh(acc[i][j][r] + vec[idx]);
            }
        }
    }
}

// ---------------------------------------------------------------------------
// Unit: one wave computes a 16m x 64n tile, K=512 (16 T), no LDS/barriers.
// A built per-lane from fp32 children, cast f16. Single MFMA per product.
// ---------------------------------------------------------------------------
__device__ void level_units(
    const float* __restrict__ h, const _Float16* __restrict__ Wf,
    const float* __restrict__ vec, float* __restrict__ out,
    int M, int gwave, int lane, bool guard)
{
    const int U = ((M + 15) / 16) * 4;
    if (gwave >= U) return;

    const int mtile = gwave >> 2;
    const int nOff = (gwave & 3) * 64;
    const size_t J0 = (size_t)(nOff >> 4);

    const int mloc = lane & 15, q = lane >> 4;
    const int m = mtile * 16 + mloc;
    const bool valid = (m < M);
    const int mc = valid ? m : (M - 1);
    const float* hb = h + (size_t)mc * 1024 + q * 8;

    f32x4 acc[4] = {};

    float4 A0[2], A1[2], B0[2], B1[2], C0[2], C1[2];
    float cc0[2], cc2[2];
    f16x8 ub[2][4];

    auto load_h = [&](int T, int buf) {
        const int k0 = T * 32;
        const bool isL = (k0 < 256);
        cc0[buf] = isL ? 1.0f : (1.0f / 3.0f);
        cc2[buf] = isL ? (1.0f / 3.0f) : 1.0f;
        const float* base = hb + (isL ? 0 : 256) + (k0 & 255);
        A0[buf] = *reinterpret_cast<const float4*>(base);
        A1[buf] = *reinterpret_cast<const float4*>(base + 4);
        B0[buf] = *reinterpret_cast<const float4*>(base + 256);
        B1[buf] = *reinterpret_cast<const float4*>(base + 260);
        C0[buf] = *reinterpret_cast<const float4*>(base + 512);
        C1[buf] = *reinterpret_cast<const float4*>(base + 516);
    };
    auto load_B = [&](int T, int buf) {
        const _Float16* p = Wf + ((J0 * 16 + T) * 64 + lane) * 8;
#pragma unroll
        for (int j = 0; j < 4; ++j)
            ub[buf][j] = *reinterpret_cast<const f16x8*>(p + (size_t)j * 8192);
    };

    load_h(0, 0);
    load_B(0, 0);

    for (int T = 0; T < 16; ++T) {
        const int b = T & 1;
        if (T < 15) { load_h(T + 1, b ^ 1); load_B(T + 1, b ^ 1); }

        constexpr float CM = 2.0f / 3.0f;
        float g[8];
        g[0] = cc0[b] * A0[b].x + CM * B0[b].x + cc2[b] * C0[b].x;
        g[1] = cc0[b] * A0[b].y + CM * B0[b].y + cc2[b] * C0[b].y;
        g[2] = cc0[b] * A0[b].z + CM * B0[b].z + cc2[b] * C0[b].z;
        g[3] = cc0[b] * A0[b].w + CM * B0[b].w + cc2[b] * C0[b].w;
        g[4] = cc0[b] * A1[b].x + CM * B1[b].x + cc2[b] * C1[b].x;
        g[5] = cc0[b] * A1[b].y + CM * B1[b].y + cc2[b] * C1[b].y;
        g[6] = cc0[b] * A1[b].z + CM * B1[b].z + cc2[b] * C1[b].z;
        g[7] = cc0[b] * A1[b].w + CM * B1[b].w + cc2[b] * C1[b].w;

        f16x8 ah;
#pragma unroll
        for (int j = 0; j < 8; ++j)
            ah[j] = (_Float16)(valid ? g[j] : 0.0f);

#pragma unroll
        for (int j = 0; j < 4; ++j)
            acc[j] = __builtin_amdgcn_mfma_f32_16x16x32_f16(ah, ub[b][j], acc[j], 0, 0, 0);
    }

    const int n16 = lane & 15;
#pragma unroll
    for (int j = 0; j < 4; ++j) {
        const int n = nOff + j * 16 + n16;
#pragma unroll
        for (int r = 0; r < 4; ++r) {
            const int mr = mtile * 16 + q * 4 + r;
            if (!guard || mr < M) {
                const size_t idx = (size_t)mr * 256 + n;
                out[idx] = fast_tanh(acc[j][r] + vec[idx]);
            }
        }
    }
}

// Standalone wave-unit level: grid = U/4 blocks of 256.
__global__ __launch_bounds__(256, 2) void cbt_units(
    const float* __restrict__ h, const _Float16* __restrict__ Wf,
    const float* __restrict__ vec, float* __restrict__ out, int M)
{
    const int gwave = blockIdx.x * 4 + (threadIdx.x >> 6);
    level_units(h, Wf, vec, out, M, gwave, threadIdx.x & 63, false);
}

// ---------------------------------------------------------------------------
// Fused tail: L3 -> L2 -> L1 -> L0 in ONE 1024-thread block (16 waves).
// Intermediates in LDS (64+16+4 KB), __syncthreads between levels (all
// threads reach it: inactive waves return from level_units first).
// ---------------------------------------------------------------------------
__global__ __launch_bounds__(1024) void cbt_tail(
    const float* __restrict__ h4, const _Float16* __restrict__ Wf,
    const float* __restrict__ vectors, float* __restrict__ d_out)
{
    __shared__ __align__(16) float h3s[64 * 256];
    __shared__ __align__(16) float h2s[16 * 256];
    __shared__ __align__(16) float h1s[4 * 256];

    const int tid = threadIdx.x;
    const int lane = tid & 63;
    const int lw = tid >> 6;   // 0..15

    const float* vec3 = vectors + (size_t)21 * 256;
    const float* vec2 = vectors + (size_t)5 * 256;
    const float* vec1 = vectors + (size_t)1 * 256;
    const float* vec0 = vectors;

    level_units(h4, Wf, vec3, h3s, 64, lw, lane, false);   // 16 units
    __syncthreads();
    level_units(h3s, Wf, vec2, h2s, 16, lw, lane, false);  // 4 units
    __syncthreads();
    level_units(h2s, Wf, vec1, h1s, 4, lw, lane, true);    // 4 units
    __syncthreads();
    level_units(h1s, Wf, vec0, d_out, 1, lw, lane, true);  // 4 units
}

// ---------------------------------------------------------------------------
extern "C" void kernel_launch(void* const* d_in, const int* in_sizes, int n_in,
                              void* d_out, int out_size, void* d_ws, size_t ws_size,
                              hipStream_t stream) {
    const float* vectors = (const float*)d_in[0];
    const float* Wl = (const float*)d_in[1];
    const float* Wr = (const float*)d_in[2];
    float* out = (float*)d_out;

    // ws layout (fp32 intermediates, distinct regions; ws ~350MB)
    float* h7 = (float*)d_ws;                           // 16384 x 256
    float* h6 = h7 + (size_t)16384 * 256;               //  4096 x 256
    float* h5 = h6 + (size_t)4096 * 256;                //  1024 x 256
    float* h4 = h5 + (size_t)1024 * 256;                //   256 x 256
    _Float16* Wf = (_Float16*)(h4 + (size_t)256 * 256); // 131072 f16

    const float* vec7 = vectors + (size_t)5461 * 256;
    const float* vec6 = vectors + (size_t)1365 * 256;
    const float* vec5 = vectors + (size_t)341 * 256;
    const float* vec4 = vectors + (size_t)85 * 256;
    const float* leaf = vectors + (size_t)21845 * 256;

    hipLaunchKernelGGL(cbt_wconv, dim3(64), dim3(256), 0, stream, Wl, Wr, Wf);
    hipLaunchKernelGGL((cbt_block<64>), dim3(256, 2), dim3(256), 0, stream,
                       leaf, Wf, vec7, h7, 16384);
    hipLaunchKernelGGL((cbt_block<32>), dim3(128, 2), dim3(256), 0, stream,
                       h7, Wf, vec6, h6, 4096);
    hipLaunchKernelGGL(cbt_units, dim3(64), dim3(256), 0, stream,
                       h6, Wf, vec5, h5, 1024);
    hipLaunchKernelGGL(cbt_units, dim3(16), dim3(256), 0, stream,
                       h5, Wf, vec4, h4, 256);
    hipLaunchKernelGGL(cbt_tail, dim3(1), dim3(1024), 0, stream,
                       h4, Wf, vectors, out);
}

// Round 9
// 285.156 us; speedup vs baseline: 4.4612x; 1.1445x over previous
//
#include <hip/hip_runtime.h>
#include <math.h>

// CBTree contraction, B=4, L=9, d=256.
// g-combine before GEMM (linearity):
//   gL[p]=sum_b lc[b]*h[4p+b], gR[p]=sum_b rc[b]*h[4p+b]
//   h_new[p] = tanh([gL|gR] @ [Wl|Wr].T + vec[p])  (M=n_par, K=512, N=256)
//
// Round 9: R8's cbt_tail burned 112us on SCRATCH SPILL — the T-loop was not
// unrolled, so A0[b]/ub[b][j] dynamic indexing demoted the double-buffer
// arrays to scratch (evidence: WRITE_SIZE=385KB for a 1KB-output kernel,
// VGPR=64). Same pathology explains R6/R7's 796us block kernel (2x the
// array state). Fix: #pragma unroll on ALL T-loops (static buffer indices ->
// registers), tail at 512 threads (2 waves/SIMD -> 256-VGPR cap).
// Precision unchanged: f16 MFMA + fp32 intermediates, absmax ~0.0039.

typedef _Float16 f16x8 __attribute__((ext_vector_type(8)));
typedef _Float16 f16x4 __attribute__((ext_vector_type(4)));
typedef float f32x4 __attribute__((ext_vector_type(4)));

__device__ __forceinline__ float fast_tanh(float x) {
    float ax = fabsf(x);
    float t = __builtin_amdgcn_exp2f(ax * -2.885390082f);  // 2*log2(e)
    float r = (1.0f - t) * __builtin_amdgcn_rcpf(1.0f + t);
    return copysignf(r, x);
}

// ---------------------------------------------------------------------------
// W swizzle: [Wl|Wr] (N=256 x K=512) -> MFMA B-fragment order, f16.
// Fragment (J,T), lane L, elem j: B[k=T*32+(L>>4)*8+j][n=J*16+(L&15)] = Wcat[n][k]
// Flat: Wf[(((J*16)+T)*64 + L)*8 + j]
// ---------------------------------------------------------------------------
__global__ __launch_bounds__(256) void cbt_wconv(
    const float* __restrict__ Wl, const float* __restrict__ Wr,
    _Float16* __restrict__ Wf)
{
    const int t = blockIdx.x * 256 + threadIdx.x;   // 0..16383
    const int L = t & 63;
    const int TJ = t >> 6;
    const int T = TJ & 15;
    const int J = TJ >> 4;
    const int n = J * 16 + (L & 15);
    const int k = T * 32 + (L >> 4) * 8;
    const float* src = (k < 256) ? (Wl + (size_t)n * 256 + k)
                                 : (Wr + (size_t)n * 256 + (k - 256));
    const float4 f0 = *reinterpret_cast<const float4*>(src);
    const float4 f1 = *reinterpret_cast<const float4*>(src + 4);
    f16x8 o;
    o[0] = (_Float16)f0.x; o[1] = (_Float16)f0.y;
    o[2] = (_Float16)f0.z; o[3] = (_Float16)f0.w;
    o[4] = (_Float16)f1.x; o[5] = (_Float16)f1.y;
    o[6] = (_Float16)f1.z; o[7] = (_Float16)f1.w;
    *reinterpret_cast<f16x8*>(Wf + (size_t)t * 8) = o;
}

// ---------------------------------------------------------------------------
// Block-GEMM level: tile BM x 128, grid(M/BM, 2), 256 threads (4 waves),
// wave-tile (BM/2) x 64, K-step 32 (16 T, FULLY UNROLLED).
// A (combined g, f16) via LDS; B register-double-buffered from Wf (L2-hot).
// ---------------------------------------------------------------------------
template <int BM>
__global__ __launch_bounds__(256, 2) void cbt_block(
    const float* __restrict__ h,       // (4*M, 256) children, fp32
    const _Float16* __restrict__ Wf,   // swizzled weights
    const float* __restrict__ vec,     // (M, 256)
    float* __restrict__ out,           // (M, 256) fp32
    int M)
{
    constexpr int MI = BM / 32;              // m-tiles per wave
    constexpr int SE = (BM == 64) ? 8 : 4;   // A elems staged per thread
    __shared__ __align__(16) _Float16 Alds[BM * 40];  // rows of 32, stride 40

    const int tid = threadIdx.x;
    const int lane = tid & 63;
    const int w = tid >> 6;
    const int wr = w >> 1, wc = w & 1;
    const int mBase = blockIdx.x * BM;
    const int nOff = blockIdx.y * 128;

    f32x4 acc[MI][4] = {};

    const int sm  = (BM == 64) ? (tid >> 2) : (tid >> 3);
    const int skq = (BM == 64) ? ((tid & 3) * 8) : ((tid & 7) * 4);
    const float* hb = h + (size_t)(mBase + sm) * 1024;

    float rr0[SE], rr1[SE], rr2[SE];
    float c0, c2;
    auto load_h = [&](int k0) {
        const bool isL = (k0 < 256);
        c0 = isL ? 1.0f : (1.0f / 3.0f);
        c2 = isL ? (1.0f / 3.0f) : 1.0f;
        const float* base = hb + (isL ? 0 : 256) + (k0 & 255) + skq;
#pragma unroll
        for (int v = 0; v < SE / 4; ++v) {
            const float4 a = *reinterpret_cast<const float4*>(base + v * 4);
            const float4 b = *reinterpret_cast<const float4*>(base + 256 + v * 4);
            const float4 c = *reinterpret_cast<const float4*>(base + 512 + v * 4);
            rr0[v*4+0] = a.x; rr0[v*4+1] = a.y; rr0[v*4+2] = a.z; rr0[v*4+3] = a.w;
            rr1[v*4+0] = b.x; rr1[v*4+1] = b.y; rr1[v*4+2] = b.z; rr1[v*4+3] = b.w;
            rr2[v*4+0] = c.x; rr2[v*4+1] = c.y; rr2[v*4+2] = c.z; rr2[v*4+3] = c.w;
        }
    };

    auto store_A = [&]() {
        constexpr float CM = 2.0f / 3.0f;
        if constexpr (SE == 8) {
            f16x8 g;
#pragma unroll
            for (int j = 0; j < 8; ++j)
                g[j] = (_Float16)(c0 * rr0[j] + CM * rr1[j] + c2 * rr2[j]);
            *reinterpret_cast<f16x8*>(&Alds[sm * 40 + skq]) = g;
        } else {
            f16x4 g;
#pragma unroll
            for (int j = 0; j < 4; ++j)
                g[j] = (_Float16)(c0 * rr0[j] + CM * rr1[j] + c2 * rr2[j]);
            *reinterpret_cast<f16x4*>(&Alds[sm * 40 + skq]) = g;
        }
    };

    f16x8 bfr[2][4];
    const size_t J0 = (size_t)(nOff >> 4) + wc * 4;
    auto load_B = [&](int T, int buf) {
        const _Float16* p = Wf + ((J0 * 16 + T) * 64 + lane) * 8;
#pragma unroll
        for (int j = 0; j < 4; ++j)
            bfr[buf][j] = *reinterpret_cast<const f16x8*>(p + (size_t)j * 8192);
    };

    load_h(0);
    load_B(0, 0);

#pragma unroll
    for (int T = 0; T < 16; ++T) {       // UNROLLED: all [2]-buffers static
        __syncthreads();
        store_A();
        __syncthreads();

        if (T < 15) {
            load_B(T + 1, (T + 1) & 1);
            load_h((T + 1) * 32);
        }

        f16x8 af[MI];
#pragma unroll
        for (int i = 0; i < MI; ++i)
            af[i] = *reinterpret_cast<const f16x8*>(
                &Alds[((wr * MI + i) * 16 + (lane & 15)) * 40 + (lane >> 4) * 8]);

#pragma unroll
        for (int i = 0; i < MI; ++i)
#pragma unroll
            for (int j = 0; j < 4; ++j)
                acc[i][j] = __builtin_amdgcn_mfma_f32_16x16x32_f16(
                    af[i], bfr[T & 1][j], acc[i][j], 0, 0, 0);
    }

    // epilogue: C/D layout col=lane&15, row=(lane>>4)*4+reg
    const int q = lane >> 4, n16 = lane & 15;
#pragma unroll
    for (int i = 0; i < MI; ++i) {
        const int mrow = mBase + (wr * MI + i) * 16 + q * 4;
#pragma unroll
        for (int j = 0; j < 4; ++j) {
            const int n = nOff + wc * 64 + j * 16 + n16;
#pragma unroll
            for (int r = 0; r < 4; ++r) {
                const size_t idx = (size_t)(mrow + r) * 256 + n;
                out[idx] = fast_tanh(acc[i][j][r] + vec[idx]);
            }
        }
    }
}

// ---------------------------------------------------------------------------
// Unit: one wave computes a 16m x 64n tile, K=512 (16 T, FULLY UNROLLED),
// no LDS/barriers. A built per-lane from fp32 children, cast f16.
// ---------------------------------------------------------------------------
__device__ void level_units(
    const float* __restrict__ h, const _Float16* __restrict__ Wf,
    const float* __restrict__ vec, float* __restrict__ out,
    int M, int gwave, int lane, bool guard)
{
    const int U = ((M + 15) / 16) * 4;
    if (gwave >= U) return;

    const int mtile = gwave >> 2;
    const int nOff = (gwave & 3) * 64;
    const size_t J0 = (size_t)(nOff >> 4);

    const int mloc = lane & 15, q = lane >> 4;
    const int m = mtile * 16 + mloc;
    const bool valid = (m < M);
    const int mc = valid ? m : (M - 1);
    const float* hb = h + (size_t)mc * 1024 + q * 8;

    f32x4 acc[4] = {};

    float4 A0[2], A1[2], B0[2], B1[2], C0[2], C1[2];
    float cc0[2], cc2[2];
    f16x8 ub[2][4];

    auto load_h = [&](int T, int buf) {
        const int k0 = T * 32;
        const bool isL = (k0 < 256);
        cc0[buf] = isL ? 1.0f : (1.0f / 3.0f);
        cc2[buf] = isL ? (1.0f / 3.0f) : 1.0f;
        const float* base = hb + (isL ? 0 : 256) + (k0 & 255);
        A0[buf] = *reinterpret_cast<const float4*>(base);
        A1[buf] = *reinterpret_cast<const float4*>(base + 4);
        B0[buf] = *reinterpret_cast<const float4*>(base + 256);
        B1[buf] = *reinterpret_cast<const float4*>(base + 260);
        C0[buf] = *reinterpret_cast<const float4*>(base + 512);
        C1[buf] = *reinterpret_cast<const float4*>(base + 516);
    };
    auto load_B = [&](int T, int buf) {
        const _Float16* p = Wf + ((J0 * 16 + T) * 64 + lane) * 8;
#pragma unroll
        for (int j = 0; j < 4; ++j)
            ub[buf][j] = *reinterpret_cast<const f16x8*>(p + (size_t)j * 8192);
    };

    load_h(0, 0);
    load_B(0, 0);

#pragma unroll
    for (int T = 0; T < 16; ++T) {       // UNROLLED: [2]-buffers stay in regs
        const int b = T & 1;
        if (T < 15) { load_h(T + 1, b ^ 1); load_B(T + 1, b ^ 1); }

        constexpr float CM = 2.0f / 3.0f;
        float g[8];
        g[0] = cc0[b] * A0[b].x + CM * B0[b].x + cc2[b] * C0[b].x;
        g[1] = cc0[b] * A0[b].y + CM * B0[b].y + cc2[b] * C0[b].y;
        g[2] = cc0[b] * A0[b].z + CM * B0[b].z + cc2[b] * C0[b].z;
        g[3] = cc0[b] * A0[b].w + CM * B0[b].w + cc2[b] * C0[b].w;
        g[4] = cc0[b] * A1[b].x + CM * B1[b].x + cc2[b] * C1[b].x;
        g[5] = cc0[b] * A1[b].y + CM * B1[b].y + cc2[b] * C1[b].y;
        g[6] = cc0[b] * A1[b].z + CM * B1[b].z + cc2[b] * C1[b].z;
        g[7] = cc0[b] * A1[b].w + CM * B1[b].w + cc2[b] * C1[b].w;

        f16x8 ah;
#pragma unroll
        for (int j = 0; j < 8; ++j)
            ah[j] = (_Float16)(valid ? g[j] : 0.0f);

#pragma unroll
        for (int j = 0; j < 4; ++j)
            acc[j] = __builtin_amdgcn_mfma_f32_16x16x32_f16(ah, ub[b][j], acc[j], 0, 0, 0);
    }

    const int n16 = lane & 15;
#pragma unroll
    for (int j = 0; j < 4; ++j) {
        const int n = nOff + j * 16 + n16;
#pragma unroll
        for (int r = 0; r < 4; ++r) {
            const int mr = mtile * 16 + q * 4 + r;
            if (!guard || mr < M) {
                const size_t idx = (size_t)mr * 256 + n;
                out[idx] = fast_tanh(acc[j][r] + vec[idx]);
            }
        }
    }
}

// Standalone wave-unit level: grid = U/4 blocks of 256.
__global__ __launch_bounds__(256, 2) void cbt_units(
    const float* __restrict__ h, const _Float16* __restrict__ Wf,
    const float* __restrict__ vec, float* __restrict__ out, int M)
{
    const int gwave = blockIdx.x * 4 + (threadIdx.x >> 6);
    level_units(h, Wf, vec, out, M, gwave, threadIdx.x & 63, false);
}

// ---------------------------------------------------------------------------
// Fused tail: L3 -> L2 -> L1 -> L0 in ONE 512-thread block (8 waves;
// 2 waves/SIMD -> 256-VGPR cap, room for the unrolled pipeline).
// Intermediates in LDS (64+16+4 KB), __syncthreads between levels.
// L3's 16 units run in 2 rounds of 8.
// ---------------------------------------------------------------------------
__global__ __launch_bounds__(512) void cbt_tail(
    const float* __restrict__ h4, const _Float16* __restrict__ Wf,
    const float* __restrict__ vectors, float* __restrict__ d_out)
{
    __shared__ __align__(16) float h3s[64 * 256];
    __shared__ __align__(16) float h2s[16 * 256];
    __shared__ __align__(16) float h1s[4 * 256];

    const int tid = threadIdx.x;
    const int lane = tid & 63;
    const int lw = tid >> 6;   // 0..7

    const float* vec3 = vectors + (size_t)21 * 256;
    const float* vec2 = vectors + (size_t)5 * 256;
    const float* vec1 = vectors + (size_t)1 * 256;
    const float* vec0 = vectors;

    level_units(h4, Wf, vec3, h3s, 64, lw, lane, false);       // units 0..7
    level_units(h4, Wf, vec3, h3s, 64, lw + 8, lane, false);   // units 8..15
    __syncthreads();
    level_units(h3s, Wf, vec2, h2s, 16, lw, lane, false);      // 4 units
    __syncthreads();
    level_units(h2s, Wf, vec1, h1s, 4, lw, lane, true);        // 4 units
    __syncthreads();
    level_units(h1s, Wf, vec0, d_out, 1, lw, lane, true);      // 4 units
}

// ---------------------------------------------------------------------------
extern "C" void kernel_launch(void* const* d_in, const int* in_sizes, int n_in,
                              void* d_out, int out_size, void* d_ws, size_t ws_size,
                              hipStream_t stream) {
    const float* vectors = (const float*)d_in[0];
    const float* Wl = (const float*)d_in[1];
    const float* Wr = (const float*)d_in[2];
    float* out = (float*)d_out;

    // ws layout (fp32 intermediates, distinct regions; ws ~350MB)
    float* h7 = (float*)d_ws;                           // 16384 x 256
    float* h6 = h7 + (size_t)16384 * 256;               //  4096 x 256
    float* h5 = h6 + (size_t)4096 * 256;                //  1024 x 256
    float* h4 = h5 + (size_t)1024 * 256;                //   256 x 256
    _Float16* Wf = (_Float16*)(h4 + (size_t)256 * 256); // 131072 f16

    const float* vec7 = vectors + (size_t)5461 * 256;
    const float* vec6 = vectors + (size_t)1365 * 256;
    const float* vec5 = vectors + (size_t)341 * 256;
    const float* vec4 = vectors + (size_t)85 * 256;
    const float* leaf = vectors + (size_t)21845 * 256;

    hipLaunchKernelGGL(cbt_wconv, dim3(64), dim3(256), 0, stream, Wl, Wr, Wf);
    hipLaunchKernelGGL((cbt_block<64>), dim3(256, 2), dim3(256), 0, stream,
                       leaf, Wf, vec7, h7, 16384);
    hipLaunchKernelGGL((cbt_block<32>), dim3(128, 2), dim3(256), 0, stream,
                       h7, Wf, vec6, h6, 4096);
    hipLaunchKernelGGL(cbt_units, dim3(64), dim3(256), 0, stream,
                       h6, Wf, vec5, h5, 1024);
    hipLaunchKernelGGL(cbt_units, dim3(16), dim3(256), 0, stream,
                       h5, Wf, vec4, h4, 256);
    hipLaunchKernelGGL(cbt_tail, dim3(1), dim3(512), 0, stream,
                       h4, Wf, vectors, out);
}